// Round 11
// baseline (12744.727 us; speedup 1.0000x reference)
//
#include <hip/hip_runtime.h>
#include <hip/hip_bf16.h>
#include <stdint.h>

typedef unsigned short u16;
typedef unsigned int   u32;
typedef unsigned long long u64;
typedef __attribute__((ext_vector_type(8))) short short8;
typedef __attribute__((ext_vector_type(4))) float f32x4;

#define T_SEQ 2048
#define NTOK  16384        // B*T = 8*2048
#define NGATE 4096         // 2 dirs * 4H(=2048)

__device__ __forceinline__ u16 f2bf(float f) {
    u32 u = __builtin_bit_cast(u32, f);
    return (u16)((u + 0x7fffu + ((u >> 16) & 1u)) >> 16);  // RNE
}
__device__ __forceinline__ float bf2f(u16 s) {
    return __builtin_bit_cast(float, (u32)s << 16);
}

// Non-temporal device-scope publish: write-through to LLC (no dirty line left
// in the producer XCD's L2 -> consumer polls skip the remote-L2 probe).
// Dword stores are atomic; the 16-bit tag travels with the value.
__device__ __forceinline__ void store_nt(u32* p, u32 v) {
    asm volatile("global_store_dword %0, %1, off sc0 sc1 nt" :: "v"(p), "v"(v) : "memory");
}

// ---------------- init: zero comm buffers (tags=0 == initial h=0) ------------
__global__ void k_init(u32* comm, int n_comm) {
    int i = blockIdx.x * blockDim.x + threadIdx.x;
    int stride = gridDim.x * blockDim.x;
    for (int k = i; k < n_comm; k += stride) comm[k] = 0u;
}

// ---------------- fp32 -> bf16 convert (x) -----------------------------------
__global__ void k_f2bf(const float* __restrict__ src, u16* __restrict__ dst, int n4) {
    int i = blockIdx.x * blockDim.x + threadIdx.x;
    if (i >= n4) return;
    float4 v = ((const float4*)src)[i];
    u32 lo = (u32)f2bf(v.x) | ((u32)f2bf(v.y) << 16);
    u32 hi = (u32)f2bf(v.z) | ((u32)f2bf(v.w) << 16);
    ((uint2*)dst)[i] = make_uint2(lo, hi);
}

// ---------------- pack Wx into transposed, gate-permuted layout --------------
// dst[n][k] (N-major, [NGATE][K]) where n = dir*2048 + pcol.
// UNIT-MAJOR/GATE-MINOR within 16-col chunks: chunk c = pcol>>4,
// col16 = pcol&15 -> uu = col16>>2, g = col16&3; unit u = c*4+uu;
// original col = g*512 + u.
__global__ void k_pack_wxT(const float* __restrict__ Wf, const float* __restrict__ Wb,
                           u16* __restrict__ dst, int K, int klog /* log2(K/8) */) {
    int gid = blockIdx.x * blockDim.x + threadIdx.x;
    if (gid >= (NGATE << klog)) return;
    int n  = gid >> klog;
    int kc = gid & ((1 << klog) - 1);
    int dir = n >> 11, pcol = n & 2047;
    int c = pcol >> 4, uu = (pcol >> 2) & 3, g = pcol & 3;
    int u = c * 4 + uu;
    int oc = g * 512 + u;
    const float* src = dir ? Wb : Wf;
    u16* d = dst + (size_t)n * K + kc * 8;
    #pragma unroll
    for (int j = 0; j < 8; j++) d[j] = f2bf(src[(size_t)(kc * 8 + j) * 2048 + oc]);
}

// ---------------- pack Wh into per-wave MFMA B-fragment order ----------------
// dst index = (((dir*128 + c)*16 + kk)*64 + lane)*8 + j   (chunk c)
// value = Wh[k = kk*32 + (lane>>4)*8 + j][col = g*512 + (c*4 + uu)],
//   with uu = (lane&15)>>2, g = lane&3  (unit-major/gate-minor).
__global__ void k_pack_whF(const float* __restrict__ Whf, const float* __restrict__ Whb,
                           u16* __restrict__ dst) {
    int gid = blockIdx.x * blockDim.x + threadIdx.x;   // 262144 total
    int lane = gid & 63, kk = (gid >> 6) & 15, c = (gid >> 10) & 127, dir = (gid >> 17) & 1;
    int col16 = lane & 15, uu = col16 >> 2, g = col16 & 3;
    int u = c * 4 + uu, oc = g * 512 + u;
    int kbase = kk * 32 + (lane >> 4) * 8;
    const float* src = dir ? Whb : Whf;
    u16* d = dst + (size_t)gid * 8;
    #pragma unroll
    for (int j = 0; j < 8; j++) d[j] = f2bf(src[(size_t)(kbase + j) * 2048 + oc]);
}

// ---------------- bf16 GEMM: C[M][NGATE] = A[M][K] @ BT[n][k]^T --------------
template <int K>
__global__ __launch_bounds__(256) void k_gemm(const u16* __restrict__ A,
                                              const u16* __restrict__ BT,
                                              u16* __restrict__ C) {
    __shared__ __align__(16) u16 a_lds[128][72];
    __shared__ __align__(16) u16 b_lds[128][72];
    const int tid = threadIdx.x;
    const int lane = tid & 63;
    const int wav = tid >> 6;
    const int wr = wav >> 1, wc = wav & 1;
    const int row0 = blockIdx.y * 128, col0 = blockIdx.x * 128;
    const int r_ld = lane & 15;
    const int k_ld = (lane >> 4) * 8;
    f32x4 acc[4][4] = {};
    for (int kt = 0; kt < K; kt += 64) {
        __syncthreads();
        #pragma unroll
        for (int it = 0; it < 4; it++) {
            int cc = tid + it * 256;
            int r = cc >> 3, ko = (cc & 7) * 8;
            *(short8*)&a_lds[r][ko] = *(const short8*)&A[(size_t)(row0 + r) * K + kt + ko];
            *(short8*)&b_lds[r][ko] = *(const short8*)&BT[(size_t)(col0 + r) * K + kt + ko];
        }
        __syncthreads();
        #pragma unroll
        for (int kk = 0; kk < 2; kk++) {
            short8 af[4], bfr[4];
            #pragma unroll
            for (int m = 0; m < 4; m++)
                af[m] = *(const short8*)&a_lds[wr * 64 + m * 16 + r_ld][kk * 32 + k_ld];
            #pragma unroll
            for (int n = 0; n < 4; n++)
                bfr[n] = *(const short8*)&b_lds[wc * 64 + n * 16 + r_ld][kk * 32 + k_ld];
            #pragma unroll
            for (int m = 0; m < 4; m++)
                #pragma unroll
                for (int n = 0; n < 4; n++)
                    acc[m][n] = __builtin_amdgcn_mfma_f32_16x16x32_bf16(af[m], bfr[n], acc[m][n], 0, 0, 0);
        }
    }
    const int rrow = (lane >> 4) * 4;
    const int rcol = lane & 15;
    #pragma unroll
    for (int m = 0; m < 4; m++)
        #pragma unroll
        for (int n = 0; n < 4; n++) {
            size_t rbase = (size_t)(row0 + wr * 64 + m * 16 + rrow);
            int col = col0 + wc * 64 + n * 16 + rcol;
            #pragma unroll
            for (int r = 0; r < 4; r++)
                C[(rbase + r) * NGATE + col] = f2bf(acc[m][n][r]);
        }
}

// ---------------- persistent LSTM scan (one layer, both directions) ----------
// r9 structure (best measured) + non-temporal write-through publish.
// grid = 16 blocks x 512 threads (8 waves): dir = bid>>3, p = bid&7. Block
// owns hidden units [p*64, p*64+64); wave w owns col16-chunks 2w, 2w+1
// (units p*64+w*8 .. +8), weights in 128 VGPRs. Per step:
//   spin: each non-own thread polls 4 tagged u64 comm words (combined, with
//   s_sleep backoff after first miss); own-slice words are NOT polled - the
//   block's own gate threads self-staged them into LDS last step.
//   stage z_pre (prefetched one step ahead) -> barrier -> MFMA z_mm ->
//   barrier -> all 512 threads: gates, publish tagged u32 (nt write-through),
//   self-stage own h into next LDS buffer, y write. LDS double-buffered.
// comm u32 = (tag16<<16)|bf16(h); tag travels atomically with value.
__global__ __launch_bounds__(512) void k_scan(
    const u16* __restrict__ pre,      // [NTOK][NGATE] bf16 (token r = b*T + t)
    const u16* __restrict__ whF,      // this layer's packed Wh fragments
    const float* __restrict__ bias_f, const float* __restrict__ bias_b,
    u16* __restrict__ y_bf,           // layer0: y0 [NTOK][1024] bf16 (else null)
    float* __restrict__ y_f32,        // layer1: d_out [NTOK][1024] f32 (else null)
    u32* __restrict__ comm)           // [dir][2 buf][8 b][512 u] tagged u32
{
    __shared__ __align__(16) u16   h_lds[2][8][520];
    __shared__ __align__(16) u16   z_pre[2][8][264];
    __shared__ __align__(16) float z_mm[2][8][260];

    const int tid = threadIdx.x;
    const int dir = (int)(blockIdx.x >> 3);
    const int p   = (int)(blockIdx.x & 7);
    const int l   = tid & 63;
    const int w   = tid >> 6;          // wave 0..7 (= batch in gate phase)

    // preload B fragments (Wh slice): 2 chunks x 16 x short8 = 128 VGPRs
    short8 bfrag[2][16];
    #pragma unroll
    for (int q = 0; q < 2; q++) {
        const u16* base = whF + ((size_t)(dir * 128 + p * 16 + 2 * w + q) * 16) * 512 + (size_t)l * 8;
        #pragma unroll
        for (int kk = 0; kk < 16; kk++) bfrag[q][kk] = *(const short8*)(base + kk * 512);
    }

    // gate-thread state: batch = w, unit j = tid&63
    float c_st = 0.f;
    const int gj  = tid & 63;
    const int u_g = p * 64 + gj;
    const float* bias = dir ? bias_b : bias_f;
    const float bi  = bias[u_g];        const float bff = bias[512 + u_g];
    const float bg  = bias[1024 + u_g]; const float bo  = bias[1536 + u_g];

    const int a_b = l & 7;             // A-frag source row (dup for rows 8-15)
    const int a_k = (l >> 4) * 8;
    const int zr  = l >> 4;            // acc row group; write when zr<2

    u32* const cb32 = comm + (size_t)dir * 8192;   // 2 bufs x 4096 per dir
    u64* const cbU  = (u64*)cb32;                  // 2 bufs x 2048 u64
    const int u2    = (2 * tid) & 511;             // unit pair this thread polls
    const int b0    = tid >> 8;                    // batch of first polled word
    const bool own  = (u2 >> 6) == p;              // own slice: never polled

    // zero-init own slice of LDS buffer 0 (initial h = 0)
    h_lds[0][w][u_g] = 0;

    // prologue: prefetch pre for step 0 (one step ahead pipeline)
    const int pr_b = tid >> 5, pr_seg = tid & 31;  // valid when tid<256
    short8 preg;
    if (tid < 256) {
        const int t0 = dir ? (T_SEQ - 1) : 0;
        preg = *(const short8*)&pre[((size_t)pr_b * T_SEQ + t0) * NGATE + dir * 2048 + p * 256 + pr_seg * 8];
    }

    for (int s = 0; s < T_SEQ; s++) {
        const int t  = dir ? (T_SEQ - 1 - s) : s;
        const int hb = s & 1;
        // (B) combined spin on 4 tagged u64 words (skip own slice entirely)
        if (!own) {
            const u64* sb = cbU + (size_t)((s + 1) & 1) * 2048;
            const u32 want = (u32)s & 0xffffu;
            u64 v0 = 0, v1 = 0, v2 = 0, v3 = 0;
            bool d0 = false, d1 = false, d2 = false, d3 = false;
            auto tagok = [&](u64 v) {
                return (((u32)(v >> 16) & 0xffffu) == want) & ((u32)(v >> 48) == want);
            };
            int spins = 0;
            for (;;) {
                if (!d0) { v0 = __hip_atomic_load(&sb[tid],        __ATOMIC_RELAXED, __HIP_MEMORY_SCOPE_AGENT); d0 = tagok(v0); }
                if (!d1) { v1 = __hip_atomic_load(&sb[tid + 512],  __ATOMIC_RELAXED, __HIP_MEMORY_SCOPE_AGENT); d1 = tagok(v1); }
                if (!d2) { v2 = __hip_atomic_load(&sb[tid + 1024], __ATOMIC_RELAXED, __HIP_MEMORY_SCOPE_AGENT); d2 = tagok(v2); }
                if (!d3) { v3 = __hip_atomic_load(&sb[tid + 1536], __ATOMIC_RELAXED, __HIP_MEMORY_SCOPE_AGENT); d3 = tagok(v3); }
                if (d0 & d1 & d2 & d3) break;
                if (spins++) __builtin_amdgcn_s_sleep(1);   // backoff after 1st miss
            }
            auto pk = [](u64 v) { return ((u32)v & 0xffffu) | ((u32)(v >> 32) << 16); };
            *(u32*)&h_lds[hb][b0 + 0][u2] = pk(v0);
            *(u32*)&h_lds[hb][b0 + 2][u2] = pk(v1);
            *(u32*)&h_lds[hb][b0 + 4][u2] = pk(v2);
            *(u32*)&h_lds[hb][b0 + 6][u2] = pk(v3);
        }
        // stage z_pre (prefetched a step ago); issue next step's prefetch
        if (tid < 256) {
            *(short8*)&z_pre[hb][pr_b][pr_seg * 8] = preg;
            if (s + 1 < T_SEQ) {
                const int t2 = dir ? (T_SEQ - 2 - s) : (s + 1);
                preg = *(const short8*)&pre[((size_t)pr_b * T_SEQ + t2) * NGATE + dir * 2048 + p * 256 + pr_seg * 8];
            }
        }
        __syncthreads();
        // (C) MFMA: z = h[s-1] @ Wh; wave w covers chunks 2w, 2w+1
        {
            f32x4 acc0 = {}, acc1 = {};
            #pragma unroll
            for (int kk = 0; kk < 16; kk++) {
                short8 a = *(const short8*)&h_lds[hb][a_b][kk * 32 + a_k];
                acc0 = __builtin_amdgcn_mfma_f32_16x16x32_bf16(a, bfrag[0][kk], acc0, 0, 0, 0);
                acc1 = __builtin_amdgcn_mfma_f32_16x16x32_bf16(a, bfrag[1][kk], acc1, 0, 0, 0);
            }
            if (zr < 2) {
                #pragma unroll
                for (int r = 0; r < 4; r++) {
                    z_mm[hb][zr * 4 + r][(2 * w + 0) * 16 + (l & 15)] = acc0[r];
                    z_mm[hb][zr * 4 + r][(2 * w + 1) * 16 + (l & 15)] = acc1[r];
                }
            }
        }
        __syncthreads();
        // (F) gates: all 512 threads (batch = w, unit = gj); conflict-free
        {
            float4 z4 = *(const float4*)&z_mm[hb][w][4 * gj];
            u64 pz    = *(const u64*)&z_pre[hb][w][4 * gj];
            float zi = z4.x + bf2f((u16)pz)         + bi;
            float zf = z4.y + bf2f((u16)(pz >> 16)) + bff;
            float zg = z4.z + bf2f((u16)(pz >> 32)) + bg;
            float zo = z4.w + bf2f((u16)(pz >> 48)) + bo;
            float ig = 1.f / (1.f + __expf(-zi));
            float fg = 1.f / (1.f + __expf(-zf));
            float gg = 2.f / (1.f + __expf(-2.f * zg)) - 1.f;
            float og = 1.f / (1.f + __expf(-zo));
            c_st = fg * c_st + ig * gg;
            float th = 2.f / (1.f + __expf(-2.f * c_st)) - 1.f;
            float hv = og * th;
            u16 hb16 = f2bf(hv);
            // publish first: non-temporal write-through to LLC (tag+value in
            // one dword; no dirty line left in producer L2)
            store_nt(&cb32[(size_t)(s & 1) * 4096 + w * 512 + u_g],
                     (u32)hb16 | ((u32)((s + 1) & 0xffff) << 16));
            // self-stage own h into next LDS buffer (skipped by polls)
            h_lds[(s + 1) & 1][w][u_g] = hb16;
            size_t rr = (size_t)w * T_SEQ + t;
            if (y_bf) y_bf[rr * 1024 + dir * 512 + u_g] = hb16;
            else      y_f32[rr * 1024 + dir * 512 + u_g] = hv;
        }
    }
}

// ---------------- host launch -------------------------------------------------
extern "C" void kernel_launch(void* const* d_in, const int* in_sizes, int n_in,
                              void* d_out, int out_size, void* d_ws, size_t ws_size,
                              hipStream_t stream) {
    const float* x    = (const float*)d_in[0];
    const float* Wx0f = (const float*)d_in[1];
    const float* Wh0f = (const float*)d_in[2];
    const float* b0f  = (const float*)d_in[3];
    const float* Wx0b = (const float*)d_in[4];
    const float* Wh0b = (const float*)d_in[5];
    const float* b0b  = (const float*)d_in[6];
    const float* Wx1f = (const float*)d_in[7];
    const float* Wh1f = (const float*)d_in[8];
    const float* b1f  = (const float*)d_in[9];
    const float* Wx1b = (const float*)d_in[10];
    const float* Wh1b = (const float*)d_in[11];
    const float* b1b  = (const float*)d_in[12];
    float* out = (float*)d_out;

    char* ws = (char*)d_ws;
    size_t off = 0;
    auto take = [&](size_t bytes) {
        char* pp = ws + off;
        off = (off + bytes + 255) & ~(size_t)255;
        return pp;
    };
    u16* pre  = (u16*)take((size_t)NTOK * NGATE * 2);   // 134 MB (reused both layers)
    u16* x_bf = (u16*)take((size_t)NTOK * 512 * 2);     // 16 MB
    u16* y0   = (u16*)take((size_t)NTOK * 1024 * 2);    // 33 MB
    u16* wxT0 = (u16*)take((size_t)NGATE * 512 * 2);    // 4 MB
    u16* wxT1 = (u16*)take((size_t)NGATE * 1024 * 2);   // 8 MB
    u16* whF  = (u16*)take((size_t)2 * 2097152 * 2);    // 8 MB (2 layers)
    u32* comm = (u32*)take((size_t)4 * 8192 * 4);       // 128 KB (2 layers x 2 dirs)

    k_init<<<32, 256, 0, stream>>>(comm, 4 * 8192);
    k_f2bf<<<8192, 256, 0, stream>>>(x, x_bf, NTOK * 512 / 4);
    k_pack_wxT<<<1024, 256, 0, stream>>>(Wx0f, Wx0b, wxT0, 512, 6);
    k_pack_wxT<<<2048, 256, 0, stream>>>(Wx1f, Wx1b, wxT1, 1024, 7);
    k_pack_whF<<<1024, 256, 0, stream>>>(Wh0f, Wh0b, whF);
    k_pack_whF<<<1024, 256, 0, stream>>>(Wh1f, Wh1b, whF + 2097152);

    // layer 0
    k_gemm<512><<<dim3(32, 128), 256, 0, stream>>>(x_bf, wxT0, pre);
    k_scan<<<16, 512, 0, stream>>>(pre, whF, b0f, b0b, y0, nullptr, comm);
    // layer 1
    k_gemm<1024><<<dim3(32, 128), 256, 0, stream>>>(y0, wxT1, pre);
    k_scan<<<16, 512, 0, stream>>>(pre, whF + 2097152, b1f, b1b, nullptr, out,
                                   comm + 2 * 8192);
}

// Round 12
// 9666.231 us; speedup vs baseline: 1.3185x; 1.3185x over previous
//
#include <hip/hip_runtime.h>
#include <hip/hip_bf16.h>
#include <stdint.h>

typedef unsigned short u16;
typedef unsigned int   u32;
typedef unsigned long long u64;
typedef __attribute__((ext_vector_type(8))) short short8;
typedef __attribute__((ext_vector_type(4))) float f32x4;

#define T_SEQ 2048
#define NTOK  16384        // B*T = 8*2048
#define NGATE 4096         // 2 dirs * 4H(=2048)

__device__ __forceinline__ u16 f2bf(float f) {
    u32 u = __builtin_bit_cast(u32, f);
    return (u16)((u + 0x7fffu + ((u >> 16) & 1u)) >> 16);  // RNE
}
__device__ __forceinline__ float bf2f(u16 s) {
    return __builtin_bit_cast(float, (u32)s << 16);
}

// ---------------- init: zero comm buffers (tags=0 == initial h=0) ------------
__global__ void k_init(u32* comm, int n_comm) {
    int i = blockIdx.x * blockDim.x + threadIdx.x;
    int stride = gridDim.x * blockDim.x;
    for (int k = i; k < n_comm; k += stride) comm[k] = 0u;
}

// ---------------- fp32 -> bf16 convert (x) -----------------------------------
__global__ void k_f2bf(const float* __restrict__ src, u16* __restrict__ dst, int n4) {
    int i = blockIdx.x * blockDim.x + threadIdx.x;
    if (i >= n4) return;
    float4 v = ((const float4*)src)[i];
    u32 lo = (u32)f2bf(v.x) | ((u32)f2bf(v.y) << 16);
    u32 hi = (u32)f2bf(v.z) | ((u32)f2bf(v.w) << 16);
    ((uint2*)dst)[i] = make_uint2(lo, hi);
}

// ---------------- pack Wx into transposed, gate-permuted layout --------------
// dst[n][k] (N-major, [NGATE][K]) where n = dir*2048 + pcol.
// UNIT-MAJOR/GATE-MINOR within 16-col chunks: chunk c = pcol>>4,
// col16 = pcol&15 -> uu = col16>>2, g = col16&3; unit u = c*4+uu;
// original col = g*512 + u.
__global__ void k_pack_wxT(const float* __restrict__ Wf, const float* __restrict__ Wb,
                           u16* __restrict__ dst, int K, int klog /* log2(K/8) */) {
    int gid = blockIdx.x * blockDim.x + threadIdx.x;
    if (gid >= (NGATE << klog)) return;
    int n  = gid >> klog;
    int kc = gid & ((1 << klog) - 1);
    int dir = n >> 11, pcol = n & 2047;
    int c = pcol >> 4, uu = (pcol >> 2) & 3, g = pcol & 3;
    int u = c * 4 + uu;
    int oc = g * 512 + u;
    const float* src = dir ? Wb : Wf;
    u16* d = dst + (size_t)n * K + kc * 8;
    #pragma unroll
    for (int j = 0; j < 8; j++) d[j] = f2bf(src[(size_t)(kc * 8 + j) * 2048 + oc]);
}

// ---------------- pack Wh into per-wave MFMA B-fragment order ----------------
// dst index = (((dir*128 + c)*16 + kk)*64 + lane)*8 + j   (chunk c)
// value = Wh[k = kk*32 + (lane>>4)*8 + j][col = g*512 + (c*4 + uu)],
//   with uu = (lane&15)>>2, g = lane&3  (unit-major/gate-minor).
__global__ void k_pack_whF(const float* __restrict__ Whf, const float* __restrict__ Whb,
                           u16* __restrict__ dst) {
    int gid = blockIdx.x * blockDim.x + threadIdx.x;   // 262144 total
    int lane = gid & 63, kk = (gid >> 6) & 15, c = (gid >> 10) & 127, dir = (gid >> 17) & 1;
    int col16 = lane & 15, uu = col16 >> 2, g = col16 & 3;
    int u = c * 4 + uu, oc = g * 512 + u;
    int kbase = kk * 32 + (lane >> 4) * 8;
    const float* src = dir ? Whb : Whf;
    u16* d = dst + (size_t)gid * 8;
    #pragma unroll
    for (int j = 0; j < 8; j++) d[j] = f2bf(src[(size_t)(kbase + j) * 2048 + oc]);
}

// ---------------- bf16 GEMM: C[M][NGATE] = A[M][K] @ BT[n][k]^T --------------
template <int K>
__global__ __launch_bounds__(256) void k_gemm(const u16* __restrict__ A,
                                              const u16* __restrict__ BT,
                                              u16* __restrict__ C) {
    __shared__ __align__(16) u16 a_lds[128][72];
    __shared__ __align__(16) u16 b_lds[128][72];
    const int tid = threadIdx.x;
    const int lane = tid & 63;
    const int wav = tid >> 6;
    const int wr = wav >> 1, wc = wav & 1;
    const int row0 = blockIdx.y * 128, col0 = blockIdx.x * 128;
    const int r_ld = lane & 15;
    const int k_ld = (lane >> 4) * 8;
    f32x4 acc[4][4] = {};
    for (int kt = 0; kt < K; kt += 64) {
        __syncthreads();
        #pragma unroll
        for (int it = 0; it < 4; it++) {
            int cc = tid + it * 256;
            int r = cc >> 3, ko = (cc & 7) * 8;
            *(short8*)&a_lds[r][ko] = *(const short8*)&A[(size_t)(row0 + r) * K + kt + ko];
            *(short8*)&b_lds[r][ko] = *(const short8*)&BT[(size_t)(col0 + r) * K + kt + ko];
        }
        __syncthreads();
        #pragma unroll
        for (int kk = 0; kk < 2; kk++) {
            short8 af[4], bfr[4];
            #pragma unroll
            for (int m = 0; m < 4; m++)
                af[m] = *(const short8*)&a_lds[wr * 64 + m * 16 + r_ld][kk * 32 + k_ld];
            #pragma unroll
            for (int n = 0; n < 4; n++)
                bfr[n] = *(const short8*)&b_lds[wc * 64 + n * 16 + r_ld][kk * 32 + k_ld];
            #pragma unroll
            for (int m = 0; m < 4; m++)
                #pragma unroll
                for (int n = 0; n < 4; n++)
                    acc[m][n] = __builtin_amdgcn_mfma_f32_16x16x32_bf16(af[m], bfr[n], acc[m][n], 0, 0, 0);
        }
    }
    const int rrow = (lane >> 4) * 4;
    const int rcol = lane & 15;
    #pragma unroll
    for (int m = 0; m < 4; m++)
        #pragma unroll
        for (int n = 0; n < 4; n++) {
            size_t rbase = (size_t)(row0 + wr * 64 + m * 16 + rrow);
            int col = col0 + wc * 64 + n * 16 + rcol;
            #pragma unroll
            for (int r = 0; r < 4; r++)
                C[(rbase + r) * NGATE + col] = f2bf(acc[m][n][r]);
        }
}

// ---------------- persistent LSTM scan (one layer, both directions) ----------
// r9 structure (best measured: 2.68us/step) + double-buffered polling.
// grid = 16 blocks x 512 threads (8 waves): dir = bid>>3, p = bid&7. Block
// owns hidden units [p*64, p*64+64); wave w owns col16-chunks 2w, 2w+1
// (units p*64+w*8 .. +8), weights in 128 VGPRs. Per step:
//   spin: each non-own thread polls 4 tagged u64 comm words with TWO load
//   sets alternating (one in flight while the other is checked -> poll
//   phase-lag halves); own-slice words are NOT polled (self-staged in LDS).
//   stage z_pre (prefetched one step ahead) -> barrier -> MFMA z_mm ->
//   barrier -> all 512 threads: gates, publish tagged u32 (agent atomic),
//   self-stage own h into next LDS buffer, y write. LDS double-buffered.
// comm u32 = (tag16<<16)|bf16(h); tag travels atomically with value.
__global__ __launch_bounds__(512) void k_scan(
    const u16* __restrict__ pre,      // [NTOK][NGATE] bf16 (token r = b*T + t)
    const u16* __restrict__ whF,      // this layer's packed Wh fragments
    const float* __restrict__ bias_f, const float* __restrict__ bias_b,
    u16* __restrict__ y_bf,           // layer0: y0 [NTOK][1024] bf16 (else null)
    float* __restrict__ y_f32,        // layer1: d_out [NTOK][1024] f32 (else null)
    u32* __restrict__ comm)           // [dir][2 buf][8 b][512 u] tagged u32
{
    __shared__ __align__(16) u16   h_lds[2][8][520];
    __shared__ __align__(16) u16   z_pre[2][8][264];
    __shared__ __align__(16) float z_mm[2][8][260];

    const int tid = threadIdx.x;
    const int dir = (int)(blockIdx.x >> 3);
    const int p   = (int)(blockIdx.x & 7);
    const int l   = tid & 63;
    const int w   = tid >> 6;          // wave 0..7 (= batch in gate phase)

    // preload B fragments (Wh slice): 2 chunks x 16 x short8 = 128 VGPRs
    short8 bfrag[2][16];
    #pragma unroll
    for (int q = 0; q < 2; q++) {
        const u16* base = whF + ((size_t)(dir * 128 + p * 16 + 2 * w + q) * 16) * 512 + (size_t)l * 8;
        #pragma unroll
        for (int kk = 0; kk < 16; kk++) bfrag[q][kk] = *(const short8*)(base + kk * 512);
    }

    // gate-thread state: batch = w, unit j = tid&63
    float c_st = 0.f;
    const int gj  = tid & 63;
    const int u_g = p * 64 + gj;
    const float* bias = dir ? bias_b : bias_f;
    const float bi  = bias[u_g];        const float bff = bias[512 + u_g];
    const float bg  = bias[1024 + u_g]; const float bo  = bias[1536 + u_g];

    const int a_b = l & 7;             // A-frag source row (dup for rows 8-15)
    const int a_k = (l >> 4) * 8;
    const int zr  = l >> 4;            // acc row group; write when zr<2

    u32* const cb32 = comm + (size_t)dir * 8192;   // 2 bufs x 4096 per dir
    u64* const cbU  = (u64*)cb32;                  // 2 bufs x 2048 u64
    const int u2    = (2 * tid) & 511;             // unit pair this thread polls
    const int b0    = tid >> 8;                    // batch of first polled word
    const bool own  = (u2 >> 6) == p;              // own slice: never polled

    // zero-init own slice of LDS buffer 0 (initial h = 0)
    h_lds[0][w][u_g] = 0;

    // prologue: prefetch pre for step 0 (one step ahead pipeline)
    const int pr_b = tid >> 5, pr_seg = tid & 31;  // valid when tid<256
    short8 preg;
    if (tid < 256) {
        const int t0 = dir ? (T_SEQ - 1) : 0;
        preg = *(const short8*)&pre[((size_t)pr_b * T_SEQ + t0) * NGATE + dir * 2048 + p * 256 + pr_seg * 8];
    }

    for (int s = 0; s < T_SEQ; s++) {
        const int t  = dir ? (T_SEQ - 1 - s) : s;
        const int hb = s & 1;
        // (B) double-buffered spin on 4 tagged u64 words (skip own slice)
        if (!own) {
            const u64* sb = cbU + (size_t)((s + 1) & 1) * 2048;
            const u32 want = (u32)s & 0xffffu;
            u64 v0 = 0, v1 = 0, v2 = 0, v3 = 0;
            bool d0 = false, d1 = false, d2 = false, d3 = false;
            auto tagok = [&](u64 v) {
                return (((u32)(v >> 16) & 0xffffu) == want) & ((u32)(v >> 48) == want);
            };
            auto upd = [&](u64 q0, u64 q1, u64 q2, u64 q3) {
                if (!d0 && tagok(q0)) { v0 = q0; d0 = true; }
                if (!d1 && tagok(q1)) { v1 = q1; d1 = true; }
                if (!d2 && tagok(q2)) { v2 = q2; d2 = true; }
                if (!d3 && tagok(q3)) { v3 = q3; d3 = true; }
            };
            // set A in flight
            u64 A0 = __hip_atomic_load(&sb[tid],        __ATOMIC_RELAXED, __HIP_MEMORY_SCOPE_AGENT);
            u64 A1 = __hip_atomic_load(&sb[tid + 512],  __ATOMIC_RELAXED, __HIP_MEMORY_SCOPE_AGENT);
            u64 A2 = __hip_atomic_load(&sb[tid + 1024], __ATOMIC_RELAXED, __HIP_MEMORY_SCOPE_AGENT);
            u64 A3 = __hip_atomic_load(&sb[tid + 1536], __ATOMIC_RELAXED, __HIP_MEMORY_SCOPE_AGENT);
            for (;;) {
                // issue set B, then check A (B flies while A is checked)
                u64 B0 = __hip_atomic_load(&sb[tid],        __ATOMIC_RELAXED, __HIP_MEMORY_SCOPE_AGENT);
                u64 B1 = __hip_atomic_load(&sb[tid + 512],  __ATOMIC_RELAXED, __HIP_MEMORY_SCOPE_AGENT);
                u64 B2 = __hip_atomic_load(&sb[tid + 1024], __ATOMIC_RELAXED, __HIP_MEMORY_SCOPE_AGENT);
                u64 B3 = __hip_atomic_load(&sb[tid + 1536], __ATOMIC_RELAXED, __HIP_MEMORY_SCOPE_AGENT);
                upd(A0, A1, A2, A3);
                if (d0 & d1 & d2 & d3) break;
                // issue set A, then check B
                A0 = __hip_atomic_load(&sb[tid],        __ATOMIC_RELAXED, __HIP_MEMORY_SCOPE_AGENT);
                A1 = __hip_atomic_load(&sb[tid + 512],  __ATOMIC_RELAXED, __HIP_MEMORY_SCOPE_AGENT);
                A2 = __hip_atomic_load(&sb[tid + 1024], __ATOMIC_RELAXED, __HIP_MEMORY_SCOPE_AGENT);
                A3 = __hip_atomic_load(&sb[tid + 1536], __ATOMIC_RELAXED, __HIP_MEMORY_SCOPE_AGENT);
                upd(B0, B1, B2, B3);
                if (d0 & d1 & d2 & d3) break;
            }
            auto pk = [](u64 v) { return ((u32)v & 0xffffu) | ((u32)(v >> 32) << 16); };
            *(u32*)&h_lds[hb][b0 + 0][u2] = pk(v0);
            *(u32*)&h_lds[hb][b0 + 2][u2] = pk(v1);
            *(u32*)&h_lds[hb][b0 + 4][u2] = pk(v2);
            *(u32*)&h_lds[hb][b0 + 6][u2] = pk(v3);
        }
        // stage z_pre (prefetched a step ago); issue next step's prefetch
        if (tid < 256) {
            *(short8*)&z_pre[hb][pr_b][pr_seg * 8] = preg;
            if (s + 1 < T_SEQ) {
                const int t2 = dir ? (T_SEQ - 2 - s) : (s + 1);
                preg = *(const short8*)&pre[((size_t)pr_b * T_SEQ + t2) * NGATE + dir * 2048 + p * 256 + pr_seg * 8];
            }
        }
        __syncthreads();
        // (C) MFMA: z = h[s-1] @ Wh; wave w covers chunks 2w, 2w+1
        {
            f32x4 acc0 = {}, acc1 = {};
            #pragma unroll
            for (int kk = 0; kk < 16; kk++) {
                short8 a = *(const short8*)&h_lds[hb][a_b][kk * 32 + a_k];
                acc0 = __builtin_amdgcn_mfma_f32_16x16x32_bf16(a, bfrag[0][kk], acc0, 0, 0, 0);
                acc1 = __builtin_amdgcn_mfma_f32_16x16x32_bf16(a, bfrag[1][kk], acc1, 0, 0, 0);
            }
            if (zr < 2) {
                #pragma unroll
                for (int r = 0; r < 4; r++) {
                    z_mm[hb][zr * 4 + r][(2 * w + 0) * 16 + (l & 15)] = acc0[r];
                    z_mm[hb][zr * 4 + r][(2 * w + 1) * 16 + (l & 15)] = acc1[r];
                }
            }
        }
        __syncthreads();
        // (F) gates: all 512 threads (batch = w, unit = gj); conflict-free
        {
            float4 z4 = *(const float4*)&z_mm[hb][w][4 * gj];
            u64 pz    = *(const u64*)&z_pre[hb][w][4 * gj];
            float zi = z4.x + bf2f((u16)pz)         + bi;
            float zf = z4.y + bf2f((u16)(pz >> 16)) + bff;
            float zg = z4.z + bf2f((u16)(pz >> 32)) + bg;
            float zo = z4.w + bf2f((u16)(pz >> 48)) + bo;
            float ig = 1.f / (1.f + __expf(-zi));
            float fg = 1.f / (1.f + __expf(-zf));
            float gg = 2.f / (1.f + __expf(-2.f * zg)) - 1.f;
            float og = 1.f / (1.f + __expf(-zo));
            c_st = fg * c_st + ig * gg;
            float th = 2.f / (1.f + __expf(-2.f * c_st)) - 1.f;
            float hv = og * th;
            u16 hb16 = f2bf(hv);
            // publish first (tag+value atomic in one word, LLC agent scope)
            __hip_atomic_store(&cb32[(size_t)(s & 1) * 4096 + w * 512 + u_g],
                               (u32)hb16 | ((u32)((s + 1) & 0xffff) << 16),
                               __ATOMIC_RELAXED, __HIP_MEMORY_SCOPE_AGENT);
            // self-stage own h into next LDS buffer (skipped by polls)
            h_lds[(s + 1) & 1][w][u_g] = hb16;
            size_t rr = (size_t)w * T_SEQ + t;
            if (y_bf) y_bf[rr * 1024 + dir * 512 + u_g] = hb16;
            else      y_f32[rr * 1024 + dir * 512 + u_g] = hv;
        }
    }
}

// ---------------- host launch -------------------------------------------------
extern "C" void kernel_launch(void* const* d_in, const int* in_sizes, int n_in,
                              void* d_out, int out_size, void* d_ws, size_t ws_size,
                              hipStream_t stream) {
    const float* x    = (const float*)d_in[0];
    const float* Wx0f = (const float*)d_in[1];
    const float* Wh0f = (const float*)d_in[2];
    const float* b0f  = (const float*)d_in[3];
    const float* Wx0b = (const float*)d_in[4];
    const float* Wh0b = (const float*)d_in[5];
    const float* b0b  = (const float*)d_in[6];
    const float* Wx1f = (const float*)d_in[7];
    const float* Wh1f = (const float*)d_in[8];
    const float* b1f  = (const float*)d_in[9];
    const float* Wx1b = (const float*)d_in[10];
    const float* Wh1b = (const float*)d_in[11];
    const float* b1b  = (const float*)d_in[12];
    float* out = (float*)d_out;

    char* ws = (char*)d_ws;
    size_t off = 0;
    auto take = [&](size_t bytes) {
        char* pp = ws + off;
        off = (off + bytes + 255) & ~(size_t)255;
        return pp;
    };
    u16* pre  = (u16*)take((size_t)NTOK * NGATE * 2);   // 134 MB (reused both layers)
    u16* x_bf = (u16*)take((size_t)NTOK * 512 * 2);     // 16 MB
    u16* y0   = (u16*)take((size_t)NTOK * 1024 * 2);    // 33 MB
    u16* wxT0 = (u16*)take((size_t)NGATE * 512 * 2);    // 4 MB
    u16* wxT1 = (u16*)take((size_t)NGATE * 1024 * 2);   // 8 MB
    u16* whF  = (u16*)take((size_t)2 * 2097152 * 2);    // 8 MB (2 layers)
    u32* comm = (u32*)take((size_t)4 * 8192 * 4);       // 128 KB (2 layers x 2 dirs)

    k_init<<<32, 256, 0, stream>>>(comm, 4 * 8192);
    k_f2bf<<<8192, 256, 0, stream>>>(x, x_bf, NTOK * 512 / 4);
    k_pack_wxT<<<1024, 256, 0, stream>>>(Wx0f, Wx0b, wxT0, 512, 6);
    k_pack_wxT<<<2048, 256, 0, stream>>>(Wx1f, Wx1b, wxT1, 1024, 7);
    k_pack_whF<<<1024, 256, 0, stream>>>(Wh0f, Wh0b, whF);
    k_pack_whF<<<1024, 256, 0, stream>>>(Wh1f, Wh1b, whF + 2097152);

    // layer 0
    k_gemm<512><<<dim3(32, 128), 256, 0, stream>>>(x_bf, wxT0, pre);
    k_scan<<<16, 512, 0, stream>>>(pre, whF, b0f, b0b, y0, nullptr, comm);
    // layer 1
    k_gemm<1024><<<dim3(32, 128), 256, 0, stream>>>(y0, wxT1, pre);
    k_scan<<<16, 512, 0, stream>>>(pre, whF + 2097152, b1f, b1b, nullptr, out,
                                   comm + 2 * 8192);
}